// Round 3
// baseline (1008.923 us; speedup 1.0000x reference)
//
#include <hip/hip_runtime.h>
#include <math.h>

#define B_SZ 512
#define S_SZ 512
#define E_NUM 8
#define F_DIM 20
#define BM 2                 // pairs per RNN block
#define CHUNK 16             // RNN steps per chunk
#define NROW (CHUNK * BM)    // 32 X/P rows per chunk
#define NCHUNK (S_SZ / CHUNK)
#define MAXBLK 520           // >= sum_e ceil(cnt_e/2) <= 516

typedef __attribute__((ext_vector_type(8))) short bf16x8;
typedef __attribute__((ext_vector_type(4))) float f32x4;
typedef __attribute__((ext_vector_type(4))) unsigned int u32x4;
#define MFMA(a, b, c) __builtin_amdgcn_mfma_f32_16x16x32_bf16(a, b, c, 0, 0, 0)

__device__ __forceinline__ unsigned short f2bf(float f) {  // RNE
  unsigned u = __float_as_uint(f);
  u += 0x7FFFu + ((u >> 16) & 1u);
  return (unsigned short)(u >> 16);
}
__device__ __forceinline__ float bf2f(unsigned short h) {
  return __uint_as_float(((unsigned)h) << 16);
}
__device__ __forceinline__ unsigned pack2_hi(float a, float b) {  // trunc pair
  return (__float_as_uint(a) >> 16) | (__float_as_uint(b) & 0xFFFF0000u);
}
__device__ __forceinline__ float hi_f(float a) {
  return __uint_as_float(__float_as_uint(a) & 0xFFFF0000u);
}
// 8 floats -> hi/lo bf16x8 via truncation split (lo captures remainder)
__device__ __forceinline__ void cvt8t(float4 a, float4 b, u32x4* hi, u32x4* lo) {
  u32x4 h, l;
  h[0] = pack2_hi(a.x, a.y); h[1] = pack2_hi(a.z, a.w);
  h[2] = pack2_hi(b.x, b.y); h[3] = pack2_hi(b.z, b.w);
  l[0] = pack2_hi(a.x - hi_f(a.x), a.y - hi_f(a.y));
  l[1] = pack2_hi(a.z - hi_f(a.z), a.w - hi_f(a.w));
  l[2] = pack2_hi(b.x - hi_f(b.x), b.y - hi_f(b.y));
  l[3] = pack2_hi(b.x * 0.f + b.z - hi_f(b.z), b.w - hi_f(b.w));
  *hi = h; *lo = l;
}
// 8 floats -> hi/lo bf16x8 via RNE split (one-time weight conversion)
__device__ __forceinline__ void cvt8r(float4 a, float4 b, bf16x8* hi, bf16x8* lo) {
  float v[8] = {a.x, a.y, a.z, a.w, b.x, b.y, b.z, b.w};
  bf16x8 h, l;
#pragma unroll
  for (int j = 0; j < 8; j++) {
    unsigned short hb = f2bf(v[j]);
    h[j] = (short)hb;
    l[j] = (short)f2bf(v[j] - bf2f(hb));
  }
  *hi = h; *lo = l;
}
__device__ __forceinline__ float ftanh(float x) {
  x = fminf(x, 15.0f);                 // avoid inf in NR (tanh(15)==1 in f32)
  float e = __expf(x + x);
  float d = e + 1.0f;
  float r;
  asm("v_rcp_f32 %0, %1" : "=v"(r) : "v"(d));
  r = r * (2.0f - d * r);              // 1 NR step -> ~1 ulp
  return fmaf(-2.0f, r, 1.0f);
}

// ---------------- Kernel 1: x_mean + logits ----------------
__global__ __launch_bounds__(512) void k_mean_logits(
    const float* __restrict__ x, const float* __restrict__ w_gate,
    float* __restrict__ logits) {
  __shared__ float sm[512];
  __shared__ float xm[128];
  int b = blockIdx.x;
  int t = threadIdx.x;
  int i = t & 127, s0 = t >> 7;
  const float* xb = x + (size_t)b * (S_SZ * 128);
  float acc = 0.f;
  for (int s = s0; s < S_SZ; s += 4) acc += xb[s * 128 + i];
  sm[t] = acc;
  __syncthreads();
  if (t < 128)
    xm[t] = (sm[t] + sm[t + 128] + sm[t + 256] + sm[t + 384]) * (1.0f / 512.0f);
  __syncthreads();
  if (t < E_NUM) {
    float acc2 = 0.f;
    for (int ii = 0; ii < 128; ii++) acc2 += xm[ii] * w_gate[ii * E_NUM + t];
    logits[b * E_NUM + t] = acc2;
  }
}

// ------- Kernel 2: top-2 gates + CV^2 loss + expert compaction -------
__global__ __launch_bounds__(512) void k_gate(
    const float* __restrict__ logits, float* __restrict__ sel_g,
    int* __restrict__ pair_b, int* __restrict__ pair_of,
    int* __restrict__ blk_e, int* __restrict__ blk_p0,
    int* __restrict__ blk_nr, int* __restrict__ nblk,
    float* __restrict__ loss_out) {
  __shared__ float gmat[512][8];
  __shared__ int cnt[8], base[8], pos[8];
  __shared__ float imps[8];
  int t = threadIdx.x;
  if (t < 8) { cnt[t] = 0; pos[t] = 0; }
  float lv[8];
#pragma unroll
  for (int e = 0; e < 8; e++) {
    lv[e] = logits[t * 8 + e];
    gmat[t][e] = 0.f;
  }
  __syncthreads();
  float v0 = -INFINITY, v1 = -INFINITY;
  int i0 = 0, i1 = 0;
#pragma unroll
  for (int e = 0; e < 8; e++) {
    float v = lv[e];
    if (v > v0) { v1 = v0; i1 = i0; v0 = v; i0 = e; }
    else if (v > v1) { v1 = v; i1 = e; }
  }
  float ex = expf(v1 - v0);
  float inv = 1.0f / (1.0f + ex);
  float g0 = inv, g1 = ex * inv;
  gmat[t][i0] = g0;
  gmat[t][i1] = g1;
  atomicAdd(&cnt[i0], 1);
  atomicAdd(&cnt[i1], 1);
  sel_g[t * 2] = g0;
  sel_g[t * 2 + 1] = g1;
  __syncthreads();
  if (t == 0) {
    int o = 0;
    for (int e = 0; e < 8; e++) { base[e] = o; o += cnt[e]; }
    int nb = 0;
    for (int e = 0; e < 8; e++)
      for (int off = 0; off < cnt[e]; off += BM) {
        blk_e[nb] = e;
        blk_p0[nb] = base[e] + off;
        blk_nr[nb] = min(BM, cnt[e] - off);
        nb++;
      }
    *nblk = nb;
  }
  if (t < 8) {
    float s = 0.f;
    for (int bb = 0; bb < 512; bb++) s += gmat[bb][t];
    imps[t] = s;
  }
  __syncthreads();
  {
    int r = atomicAdd(&pos[i0], 1);
    int p = base[i0] + r;
    pair_b[p] = t;
    pair_of[t * 2] = p;
  }
  {
    int r = atomicAdd(&pos[i1], 1);
    int p = base[i1] + r;
    pair_b[p] = t;
    pair_of[t * 2 + 1] = p;
  }
  if (t == 0) {
    float mi = 0.f, ml = 0.f;
#pragma unroll
    for (int e = 0; e < 8; e++) { mi += imps[e]; ml += (float)cnt[e]; }
    mi *= 0.125f; ml *= 0.125f;
    float vi = 0.f, vl = 0.f;
#pragma unroll
    for (int e = 0; e < 8; e++) {
      float di = imps[e] - mi; vi += di * di;
      float dl = (float)cnt[e] - ml; vl += dl * dl;
    }
    vi *= (1.0f / 7.0f);
    vl *= (1.0f / 7.0f);
    loss_out[0] = 0.01f * (vi / (mi * mi + 1e-10f) + vl / (ml * ml + 1e-10f));
  }
}

// -------- Kernel 3: fused x-proj + recurrent MFMA RNN, BM=2 --------
// 4 waves/block, wave owns 2 of 8 h-tiles. W_ih+W_hh hi/lo fragments in
// VGPRs. H (2 rows) and P read with replicated-row broadcast fragments.
__global__ __launch_bounds__(256, 2) void k_rnn(
    const float* __restrict__ x, const float* __restrict__ W_ih,
    const float* __restrict__ W_hh, const float* __restrict__ b_ih,
    const float* __restrict__ b_hh, const float* __restrict__ fc1_w,
    const float* __restrict__ fc1_b, const float* __restrict__ fc2_w,
    const float* __restrict__ fc2_b, const int* __restrict__ pair_b,
    const int* __restrict__ blk_e, const int* __restrict__ blk_p0,
    const int* __restrict__ blk_nr, const int* __restrict__ nblk,
    float* __restrict__ outp) {
  __shared__ unsigned short sXh[NROW * 128], sXl[NROW * 128];  // 16 KB
  __shared__ float sP[NROW * 128];                             // 16 KB
  __shared__ unsigned short sHh[2][BM * 128], sHl[2][BM * 128];// 2 KB
  __shared__ float sZ[BM * F_DIM];

  int blk = blockIdx.x;
  if (blk >= *nblk) return;
  int e = blk_e[blk], p0 = blk_p0[blk], nr = blk_nr[blk];
  int tid = threadIdx.x;
  int lane = tid & 63, g = lane >> 4, ln = lane & 15;
  int MT0 = (tid >> 6) * 2;

  // ---- W_hh / W_ih fragments straight from global into registers ----
  bf16x8 whh_h[2][4], whh_l[2][4], wih_h[2][4], wih_l[2][4];
#pragma unroll
  for (int mt = 0; mt < 2; mt++) {
    int row = (MT0 + mt) * 16 + ln;
    const float* bh = W_hh + (size_t)e * 16384 + row * 128;
    const float* bi = W_ih + (size_t)e * 16384 + row * 128;
#pragma unroll
    for (int ks = 0; ks < 4; ks++) {
      int k0 = ks * 32 + g * 8;
      cvt8r(*(const float4*)(bh + k0), *(const float4*)(bh + k0 + 4),
            &whh_h[mt][ks], &whh_l[mt][ks]);
      cvt8r(*(const float4*)(bi + k0), *(const float4*)(bi + k0 + 4),
            &wih_h[mt][ks], &wih_l[mt][ks]);
    }
  }
  f32x4 biasv[2];
#pragma unroll
  for (int mt = 0; mt < 2; mt++)
#pragma unroll
    for (int r = 0; r < 4; r++) {
      int h = (MT0 + mt) * 16 + g * 4 + r;
      biasv[mt][r] = b_ih[e * 128 + h] + b_hh[e * 128 + h];
    }
  if (tid < BM * 128) { sHh[0][tid] = 0; sHl[0][tid] = 0; }

  // x prefetch: thread -> row n = tid>>3 (0..31), 16 floats at k0=(tid&7)*16
  int xn = tid >> 3, xk0 = (tid & 7) * 16;
  int pp = xn & 1;
  int bidx = pair_b[p0 + (pp < nr ? pp : 0)];
  const float* xbase = x + (size_t)bidx * (S_SZ * 128) + (xn >> 1) * 128 + xk0;
  float4 xr[4];
#pragma unroll
  for (int j = 0; j < 4; j++) xr[j] = *(const float4*)(xbase + j * 4);
  int swz = (xn & 7) << 3;

#pragma unroll 1
  for (int c = 0; c < NCHUNK; c++) {
    {  // stage X (hi/lo, swizzled)
      u32x4 h0, l0;
      cvt8t(xr[0], xr[1], &h0, &l0);
      int el = (xn * 128 + xk0) ^ swz;
      *(u32x4*)&sXh[el] = h0;
      *(u32x4*)&sXl[el] = l0;
      cvt8t(xr[2], xr[3], &h0, &l0);
      el = (xn * 128 + xk0 + 8) ^ swz;
      *(u32x4*)&sXh[el] = h0;
      *(u32x4*)&sXl[el] = l0;
    }
    __syncthreads();
    // ---- x-projection: P = X @ W_ih^T + (b_ih + b_hh) ----
#pragma unroll
    for (int nt = 0; nt < 2; nt++) {
      bf16x8 Bh[4], Bl[4];
      int r = nt * 16 + ln;
      int rsw = (r & 7) << 3;
#pragma unroll
      for (int ks = 0; ks < 4; ks++) {
        int el = (r * 128 + ks * 32 + g * 8) ^ rsw;
        Bh[ks] = *(const bf16x8*)&sXh[el];
        Bl[ks] = *(const bf16x8*)&sXl[el];
      }
#pragma unroll
      for (int mt = 0; mt < 2; mt++) {
        f32x4 aA = biasv[mt];
        f32x4 aB = {0.f, 0.f, 0.f, 0.f}, aC = {0.f, 0.f, 0.f, 0.f};
#pragma unroll
        for (int ks = 0; ks < 4; ks++) aA = MFMA(wih_h[mt][ks], Bh[ks], aA);
#pragma unroll
        for (int ks = 0; ks < 4; ks++) aB = MFMA(wih_l[mt][ks], Bh[ks], aB);
#pragma unroll
        for (int ks = 0; ks < 4; ks++) aC = MFMA(wih_h[mt][ks], Bl[ks], aC);
        f32x4 pv = aA + aB + aC;
        int el = (r * 128 + (MT0 + mt) * 16 + g * 4) ^ ((r & 7) << 2);
        *(f32x4*)&sP[el] = pv;
      }
    }
    if (c < NCHUNK - 1) {  // prefetch next chunk's x
#pragma unroll
      for (int j = 0; j < 4; j++)
        xr[j] = *(const float4*)(xbase + (c + 1) * (CHUNK * 128) + j * 4);
    }
    __syncthreads();
    // ---- CHUNK recurrent steps (fully unrolled; const ds offsets) ----
#pragma unroll
    for (int s = 0; s < CHUNK; s++) {
      int rb = s & 1;
      int hr = ln & 1;  // replicated-row broadcast read
      bf16x8 Hh[4], Hl[4];
#pragma unroll
      for (int ks = 0; ks < 4; ks++) {
        int el = (hr * 128 + ks * 32 + g * 8) ^ (hr << 3);
        Hh[ks] = *(const bf16x8*)&sHh[rb][el];
        Hl[ks] = *(const bf16x8*)&sHl[rb][el];
      }
      f32x4 pre[2];
#pragma unroll
      for (int mt = 0; mt < 2; mt++) {
        int prow = s * 2 + hr;
        int el = (prow * 128 + (MT0 + mt) * 16 + g * 4) ^ ((prow & 7) << 2);
        f32x4 aA = *(const f32x4*)&sP[el];
        f32x4 aB = {0.f, 0.f, 0.f, 0.f}, aC = {0.f, 0.f, 0.f, 0.f};
#pragma unroll
        for (int ks = 0; ks < 4; ks++) aA = MFMA(whh_h[mt][ks], Hh[ks], aA);
#pragma unroll
        for (int ks = 0; ks < 4; ks++) aB = MFMA(whh_l[mt][ks], Hh[ks], aB);
#pragma unroll
        for (int ks = 0; ks < 4; ks++) aC = MFMA(whh_h[mt][ks], Hl[ks], aC);
        pre[mt] = aA + aB + aC;
      }
      if (ln < BM) {
#pragma unroll
        for (int mt = 0; mt < 2; mt++) {
          float t0 = ftanh(pre[mt][0]);
          float t1 = ftanh(pre[mt][1]);
          float t2 = ftanh(pre[mt][2]);
          float t3 = ftanh(pre[mt][3]);
          uint2 hv = {pack2_hi(t0, t1), pack2_hi(t2, t3)};
          uint2 lv = {pack2_hi(t0 - hi_f(t0), t1 - hi_f(t1)),
                      pack2_hi(t2 - hi_f(t2), t3 - hi_f(t3))};
          int el = (ln * 128 + (MT0 + mt) * 16 + g * 4) ^ (ln << 3);
          *(uint2*)&sHh[rb ^ 1][el] = hv;
          *(uint2*)&sHl[rb ^ 1][el] = lv;
        }
      }
      __syncthreads();
    }
  }
  // ---- MLP head ----
  if (tid < BM * F_DIM) {
    int r = tid / F_DIM, f = tid % F_DIM;
    float acc = fc1_b[e * F_DIM + f];
    const float* w1 = fc1_w + (size_t)e * (F_DIM * 128) + f * 128;
    for (int k = 0; k < 128; k++) {
      int el = (r * 128 + k) ^ (r << 3);
      acc += (bf2f(sHh[0][el]) + bf2f(sHl[0][el])) * w1[k];
    }
    sZ[r * F_DIM + f] = ftanh(acc);
  }
  __syncthreads();
  if (tid < BM) {
    float acc = fc2_b[e];
#pragma unroll
    for (int f = 0; f < F_DIM; f++)
      acc += sZ[tid * F_DIM + f] * fc2_w[e * F_DIM + f];
    if (tid < nr) outp[p0 + tid] = acc;
  }
}

// ---------------- Kernel 4: weighted combine ----------------
__global__ void k_combine(const float* __restrict__ sel_g,
                          const int* __restrict__ pair_of,
                          const float* __restrict__ outp,
                          float* __restrict__ y) {
  int b = blockIdx.x * blockDim.x + threadIdx.x;
  if (b < B_SZ)
    y[b] = sel_g[2 * b] * outp[pair_of[2 * b]] +
           sel_g[2 * b + 1] * outp[pair_of[2 * b + 1]];
}

extern "C" void kernel_launch(void* const* d_in, const int* in_sizes, int n_in,
                              void* d_out, int out_size, void* d_ws,
                              size_t ws_size, hipStream_t stream) {
  (void)in_sizes; (void)n_in; (void)out_size; (void)ws_size;
  const float* x      = (const float*)d_in[0];
  const float* w_gate = (const float*)d_in[1];
  const float* W_ih   = (const float*)d_in[2];
  const float* W_hh   = (const float*)d_in[3];
  const float* b_ih   = (const float*)d_in[4];
  const float* b_hh   = (const float*)d_in[5];
  const float* fc1_w  = (const float*)d_in[6];
  const float* fc1_b  = (const float*)d_in[7];
  const float* fc2_w  = (const float*)d_in[8];
  const float* fc2_b  = (const float*)d_in[9];
  float* out = (float*)d_out;  // [0..511] = y, [512] = loss

  float* logits = (float*)d_ws;            // 4096 f32
  float* sel_g  = logits + 4096;           // 1024 f32
  int*   pair_b = (int*)(sel_g + 1024);    // 1024 i32
  int*   pair_of= pair_b + 1024;           // 1024 i32
  int*   blk_e  = pair_of + 1024;          // 640 i32
  int*   blk_p0 = blk_e + 640;             // 640 i32
  int*   blk_nr = blk_p0 + 640;            // 640 i32
  int*   nblk   = blk_nr + 640;            // 8 i32
  float* outp   = (float*)(nblk + 8);      // 1024 f32

  k_mean_logits<<<B_SZ, 512, 0, stream>>>(x, w_gate, logits);
  k_gate<<<1, 512, 0, stream>>>(logits, sel_g, pair_b, pair_of, blk_e, blk_p0,
                                blk_nr, nblk, out + 512);
  k_rnn<<<MAXBLK, 256, 0, stream>>>(x, W_ih, W_hh, b_ih, b_hh, fc1_w, fc1_b,
                                    fc2_w, fc2_b, pair_b, blk_e, blk_p0,
                                    blk_nr, nblk, outp);
  k_combine<<<2, 256, 0, stream>>>(sel_g, pair_of, outp, out);
}

// Round 4
// 707.841 us; speedup vs baseline: 1.4254x; 1.4254x over previous
//
#include <hip/hip_runtime.h>
#include <math.h>

#define B_SZ 512
#define S_SZ 512
#define E_NUM 8
#define F_DIM 20
#define BM 16          // pairs per RNN block (full MFMA N-tile)
#define MAXBLK 72      // >= sum_e ceil(cnt_e/16) <= 71

typedef __attribute__((ext_vector_type(8))) short bf16x8;
typedef __attribute__((ext_vector_type(4))) float f32x4;
typedef __attribute__((ext_vector_type(4))) unsigned int u32x4;
#define MFMA(a, b, c) __builtin_amdgcn_mfma_f32_16x16x32_bf16(a, b, c, 0, 0, 0)

__device__ __forceinline__ unsigned short f2bf(float f) {  // RNE
  unsigned u = __float_as_uint(f);
  u += 0x7FFFu + ((u >> 16) & 1u);
  return (unsigned short)(u >> 16);
}
__device__ __forceinline__ float bf2f(unsigned short h) {
  return __uint_as_float(((unsigned)h) << 16);
}
__device__ __forceinline__ unsigned pack2_hi(float a, float b) {  // trunc pair
  return (__float_as_uint(a) >> 16) | (__float_as_uint(b) & 0xFFFF0000u);
}
__device__ __forceinline__ float hi_f(float a) {
  return __uint_as_float(__float_as_uint(a) & 0xFFFF0000u);
}
// 8 floats -> hi/lo bf16x8 via truncation split
__device__ __forceinline__ void cvtX(const float4 a, const float4 b,
                                     bf16x8* hi, bf16x8* lo) {
  u32x4 h, l;
  h[0] = pack2_hi(a.x, a.y); h[1] = pack2_hi(a.z, a.w);
  h[2] = pack2_hi(b.x, b.y); h[3] = pack2_hi(b.z, b.w);
  l[0] = pack2_hi(a.x - hi_f(a.x), a.y - hi_f(a.y));
  l[1] = pack2_hi(a.z - hi_f(a.z), a.w - hi_f(a.w));
  l[2] = pack2_hi(b.x - hi_f(b.x), b.y - hi_f(b.y));
  l[3] = pack2_hi(b.z - hi_f(b.z), b.w - hi_f(b.w));
  *hi = *(bf16x8*)&h;
  *lo = *(bf16x8*)&l;
}
// 8 floats -> hi/lo bf16x8 via RNE split (one-time weight conversion)
__device__ __forceinline__ void cvt8r(float4 a, float4 b, bf16x8* hi, bf16x8* lo) {
  float v[8] = {a.x, a.y, a.z, a.w, b.x, b.y, b.z, b.w};
  bf16x8 h, l;
#pragma unroll
  for (int j = 0; j < 8; j++) {
    unsigned short hb = f2bf(v[j]);
    h[j] = (short)hb;
    l[j] = (short)f2bf(v[j] - bf2f(hb));
  }
  *hi = h; *lo = l;
}
__device__ __forceinline__ float ftanh(float x) {
  float e = __expf(x + x);  // x->+inf: e=inf -> rcp=0 -> 1; x->-inf: e=0 -> -1
  float r;
  asm("v_rcp_f32 %0, %1" : "=v"(r) : "v"(e + 1.0f));
  return fmaf(-2.0f, r, 1.0f);
}

// raw barrier: no compiler vmcnt(0) drain -> global prefetch stays in flight
#define BAR() do {                                        \
  asm volatile("s_waitcnt lgkmcnt(0)" ::: "memory");      \
  __builtin_amdgcn_s_barrier();                           \
  asm volatile("" ::: "memory");                          \
} while (0)

// ---------------- Kernel 1: x_mean + logits ----------------
__global__ __launch_bounds__(512) void k_mean_logits(
    const float* __restrict__ x, const float* __restrict__ w_gate,
    float* __restrict__ logits) {
  __shared__ float sm[512];
  __shared__ float xm[128];
  int b = blockIdx.x;
  int t = threadIdx.x;
  int i = t & 127, s0 = t >> 7;
  const float* xb = x + (size_t)b * (S_SZ * 128);
  float acc = 0.f;
  for (int s = s0; s < S_SZ; s += 4) acc += xb[s * 128 + i];
  sm[t] = acc;
  __syncthreads();
  if (t < 128)
    xm[t] = (sm[t] + sm[t + 128] + sm[t + 256] + sm[t + 384]) * (1.0f / 512.0f);
  __syncthreads();
  if (t < E_NUM) {
    float acc2 = 0.f;
    for (int ii = 0; ii < 128; ii++) acc2 += xm[ii] * w_gate[ii * E_NUM + t];
    logits[b * E_NUM + t] = acc2;
  }
}

// ------- Kernel 2: top-2 gates + CV^2 loss + expert compaction -------
__global__ __launch_bounds__(512) void k_gate(
    const float* __restrict__ logits, float* __restrict__ sel_g,
    int* __restrict__ pair_b, int* __restrict__ pair_of,
    int* __restrict__ blk_e, int* __restrict__ blk_p0,
    int* __restrict__ blk_nr, int* __restrict__ nblk,
    float* __restrict__ loss_out) {
  __shared__ float gmat[512][8];
  __shared__ int cnt[8], base[8], pos[8];
  __shared__ float imps[8];
  int t = threadIdx.x;
  if (t < 8) { cnt[t] = 0; pos[t] = 0; }
  float lv[8];
#pragma unroll
  for (int e = 0; e < 8; e++) {
    lv[e] = logits[t * 8 + e];
    gmat[t][e] = 0.f;
  }
  __syncthreads();
  float v0 = -INFINITY, v1 = -INFINITY;
  int i0 = 0, i1 = 0;
#pragma unroll
  for (int e = 0; e < 8; e++) {
    float v = lv[e];
    if (v > v0) { v1 = v0; i1 = i0; v0 = v; i0 = e; }
    else if (v > v1) { v1 = v; i1 = e; }
  }
  float ex = expf(v1 - v0);
  float inv = 1.0f / (1.0f + ex);
  float g0 = inv, g1 = ex * inv;
  gmat[t][i0] = g0;
  gmat[t][i1] = g1;
  atomicAdd(&cnt[i0], 1);
  atomicAdd(&cnt[i1], 1);
  sel_g[t * 2] = g0;
  sel_g[t * 2 + 1] = g1;
  __syncthreads();
  if (t == 0) {
    int o = 0;
    for (int e = 0; e < 8; e++) { base[e] = o; o += cnt[e]; }
    int nb = 0;
    for (int e = 0; e < 8; e++)
      for (int off = 0; off < cnt[e]; off += BM) {
        blk_e[nb] = e;
        blk_p0[nb] = base[e] + off;
        blk_nr[nb] = min(BM, cnt[e] - off);
        nb++;
      }
    *nblk = nb;
  }
  if (t < 8) {
    float s = 0.f;
    for (int bb = 0; bb < 512; bb++) s += gmat[bb][t];
    imps[t] = s;
  }
  __syncthreads();
  {
    int r = atomicAdd(&pos[i0], 1);
    int p = base[i0] + r;
    pair_b[p] = t;
    pair_of[t * 2] = p;
  }
  {
    int r = atomicAdd(&pos[i1], 1);
    int p = base[i1] + r;
    pair_b[p] = t;
    pair_of[t * 2 + 1] = p;
  }
  if (t == 0) {
    float mi = 0.f, ml = 0.f;
#pragma unroll
    for (int e = 0; e < 8; e++) { mi += imps[e]; ml += (float)cnt[e]; }
    mi *= 0.125f; ml *= 0.125f;
    float vi = 0.f, vl = 0.f;
#pragma unroll
    for (int e = 0; e < 8; e++) {
      float di = imps[e] - mi; vi += di * di;
      float dl = (float)cnt[e] - ml; vl += dl * dl;
    }
    vi *= (1.0f / 7.0f);
    vl *= (1.0f / 7.0f);
    loss_out[0] = 0.01f * (vi / (mi * mi + 1e-10f) + vl / (ml * ml + 1e-10f));
  }
}

// -------- Kernel 3: BM=16 fused RNN. 4 waves x 2 M-tiles; x global->reg;
// P in registers; only H (16KB) round-trips LDS; raw barriers (no vm drain).
__global__ __launch_bounds__(256, 1) void k_rnn(
    const float* __restrict__ x, const float* __restrict__ W_ih,
    const float* __restrict__ W_hh, const float* __restrict__ b_ih,
    const float* __restrict__ b_hh, const float* __restrict__ fc1_w,
    const float* __restrict__ fc1_b, const float* __restrict__ fc2_w,
    const float* __restrict__ fc2_b, const int* __restrict__ pair_b,
    const int* __restrict__ blk_e, const int* __restrict__ blk_p0,
    const int* __restrict__ blk_nr, const int* __restrict__ nblk,
    float* __restrict__ outp) {
  __shared__ unsigned short sH[2][2][BM * 128];  // [parity][hi/lo] 16 KB
  __shared__ float sZ[BM * F_DIM];

  int blk = blockIdx.x;
  if (blk >= *nblk) return;
  int e = blk_e[blk], p0 = blk_p0[blk], nr = blk_nr[blk];
  int tid = threadIdx.x;
  int lane = tid & 63, g = lane >> 4, ln = lane & 15;
  int MT0 = (tid >> 6) * 2;

  // ---- W fragments straight from global into registers (RNE hi/lo) ----
  bf16x8 whh_h[2][4], whh_l[2][4], wih_h[2][4], wih_l[2][4];
#pragma unroll
  for (int mt = 0; mt < 2; mt++) {
    int row = (MT0 + mt) * 16 + ln;
    const float* bh = W_hh + (size_t)e * 16384 + row * 128;
    const float* bi = W_ih + (size_t)e * 16384 + row * 128;
#pragma unroll
    for (int ks = 0; ks < 4; ks++) {
      int k0 = ks * 32 + g * 8;
      cvt8r(*(const float4*)(bh + k0), *(const float4*)(bh + k0 + 4),
            &whh_h[mt][ks], &whh_l[mt][ks]);
      cvt8r(*(const float4*)(bi + k0), *(const float4*)(bi + k0 + 4),
            &wih_h[mt][ks], &wih_l[mt][ks]);
    }
  }
  f32x4 biasv[2];
#pragma unroll
  for (int mt = 0; mt < 2; mt++)
#pragma unroll
    for (int r = 0; r < 4; r++) {
      int h = (MT0 + mt) * 16 + g * 4 + r;
      biasv[mt][r] = b_ih[e * 128 + h] + b_hh[e * 128 + h];
    }
  // zero parity-0 H (hi+lo = first 8 KB)
#pragma unroll
  for (int it = 0; it < 8; it++) ((unsigned int*)sH)[tid + it * 256] = 0;

  // per-lane x pointer: this lane's pair row, k-offset g*8 floats
  int bidx = pair_b[p0 + (ln < nr ? ln : 0)];
  const char* xlb = (const char*)x + (size_t)bidx * (S_SZ * 512) + g * 32;

  // LDS byte offsets (XOR swizzle on bits 4-6; all offsets < 4096)
  int swz = (ln & 7) << 4;
  int rdoff[4], wroff[2][2];
#pragma unroll
  for (int ks = 0; ks < 4; ks++) rdoff[ks] = (ln * 256 + ks * 64 + g * 16) ^ swz;
#pragma unroll
  for (int mt = 0; mt < 2; mt++)
#pragma unroll
    for (int c = 0; c < 2; c++)
      wroff[mt][c] = (ln * 256 + (MT0 + mt) * 32 + g * 8 + c * 4) ^ swz;
  char* hb = (char*)&sH[0][0][0];

  const f32x4 Z4 = {0.f, 0.f, 0.f, 0.f};
  f32x4 Pc0, Pc1;
  float4 xr0[8], xr1[8], xr2[8];

#define LOADX(XR, S0)                                                        \
  _Pragma("unroll") for (int j = 0; j < 8; j++)                              \
      XR[j] = *(const float4*)(xlb + (size_t)(S0) * 512 + (j >> 1) * 128 +   \
                               (j & 1) * 16);

#define XPROJ(XU)                                                            \
  do {                                                                       \
    bf16x8 Xh[4], Xl[4];                                                     \
    _Pragma("unroll") for (int ks = 0; ks < 4; ks++)                         \
        cvtX(XU[2 * ks], XU[2 * ks + 1], &Xh[ks], &Xl[ks]);                  \
    {                                                                        \
      f32x4 pA = biasv[0], pB = Z4, pC = Z4;                                 \
      _Pragma("unroll") for (int ks = 0; ks < 4; ks++)                       \
          pA = MFMA(wih_h[0][ks], Xh[ks], pA);                               \
      _Pragma("unroll") for (int ks = 0; ks < 4; ks++)                       \
          pB = MFMA(wih_l[0][ks], Xh[ks], pB);                               \
      _Pragma("unroll") for (int ks = 0; ks < 4; ks++)                       \
          pC = MFMA(wih_h[0][ks], Xl[ks], pC);                               \
      Pc0 = pA + pB + pC;                                                    \
    }                                                                        \
    {                                                                        \
      f32x4 pA = biasv[1], pB = Z4, pC = Z4;                                 \
      _Pragma("unroll") for (int ks = 0; ks < 4; ks++)                       \
          pA = MFMA(wih_h[1][ks], Xh[ks], pA);                               \
      _Pragma("unroll") for (int ks = 0; ks < 4; ks++)                       \
          pB = MFMA(wih_l[1][ks], Xh[ks], pB);                               \
      _Pragma("unroll") for (int ks = 0; ks < 4; ks++)                       \
          pC = MFMA(wih_h[1][ks], Xl[ks], pC);                               \
      Pc1 = pA + pB + pC;                                                    \
    }                                                                        \
  } while (0)

#define HWRITE(PRE, MT, PAR)                                                 \
  do {                                                                       \
    float t0 = ftanh(PRE[0]), t1 = ftanh(PRE[1]);                            \
    float t2 = ftanh(PRE[2]), t3 = ftanh(PRE[3]);                            \
    unsigned hw0 = pack2_hi(t0, t1), hw1 = pack2_hi(t2, t3);                 \
    unsigned lw0 = pack2_hi(t0 - hi_f(t0), t1 - hi_f(t1));                   \
    unsigned lw1 = pack2_hi(t2 - hi_f(t2), t3 - hi_f(t3));                   \
    *(unsigned*)(hb + ((PAR) ^ 1) * 8192 + wroff[MT][0]) = hw0;              \
    *(unsigned*)(hb + ((PAR) ^ 1) * 8192 + wroff[MT][1]) = hw1;              \
    *(unsigned*)(hb + ((PAR) ^ 1) * 8192 + 4096 + wroff[MT][0]) = lw0;       \
    *(unsigned*)(hb + ((PAR) ^ 1) * 8192 + 4096 + wroff[MT][1]) = lw1;       \
  } while (0)

#define STEP(S, XU, XN, PAR, DOLOAD, DOXP)                                   \
  do {                                                                       \
    bf16x8 Hh[4], Hl[4];                                                     \
    _Pragma("unroll") for (int ks = 0; ks < 4; ks++) {                       \
      Hh[ks] = *(const bf16x8*)(hb + (PAR) * 8192 + rdoff[ks]);              \
      Hl[ks] = *(const bf16x8*)(hb + (PAR) * 8192 + 4096 + rdoff[ks]);       \
    }                                                                        \
    if (DOLOAD) { LOADX(XN, (S) + 3); }                                      \
    f32x4 pre0, pre1;                                                        \
    {                                                                        \
      f32x4 aA = Pc0, aB = Z4, aC = Z4;                                      \
      _Pragma("unroll") for (int ks = 0; ks < 4; ks++)                       \
          aA = MFMA(whh_h[0][ks], Hh[ks], aA);                               \
      _Pragma("unroll") for (int ks = 0; ks < 4; ks++)                       \
          aB = MFMA(whh_l[0][ks], Hh[ks], aB);                               \
      _Pragma("unroll") for (int ks = 0; ks < 4; ks++)                       \
          aC = MFMA(whh_h[0][ks], Hl[ks], aC);                               \
      pre0 = aA + aB + aC;                                                   \
    }                                                                        \
    {                                                                        \
      f32x4 aA = Pc1, aB = Z4, aC = Z4;                                      \
      _Pragma("unroll") for (int ks = 0; ks < 4; ks++)                       \
          aA = MFMA(whh_h[1][ks], Hh[ks], aA);                               \
      _Pragma("unroll") for (int ks = 0; ks < 4; ks++)                       \
          aB = MFMA(whh_l[1][ks], Hh[ks], aB);                               \
      _Pragma("unroll") for (int ks = 0; ks < 4; ks++)                       \
          aC = MFMA(whh_h[1][ks], Hl[ks], aC);                               \
      pre1 = aA + aB + aC;                                                   \
    }                                                                        \
    if (DOXP) { XPROJ(XU); }                                                 \
    HWRITE(pre0, 0, PAR);                                                    \
    HWRITE(pre1, 1, PAR);                                                    \
    BAR();                                                                   \
  } while (0)

  LOADX(xr0, 0);
  LOADX(xr1, 1);
  LOADX(xr2, 2);
  XPROJ(xr0);  // P for step 0
  BAR();       // H zeros visible

#pragma unroll 1
  for (int s6 = 0; s6 < 504; s6 += 6) {
    STEP(s6 + 0, xr1, xr0, 0, 1, 1);
    STEP(s6 + 1, xr2, xr1, 1, 1, 1);
    STEP(s6 + 2, xr0, xr2, 0, 1, 1);
    STEP(s6 + 3, xr1, xr0, 1, 1, 1);
    STEP(s6 + 4, xr2, xr1, 0, 1, 1);
    STEP(s6 + 5, xr0, xr2, 1, 1, 1);
  }
  STEP(504, xr1, xr0, 0, 1, 1);
  STEP(505, xr2, xr1, 1, 1, 1);
  STEP(506, xr0, xr2, 0, 1, 1);
  STEP(507, xr1, xr0, 1, 1, 1);
  STEP(508, xr2, xr1, 0, 1, 1);
  STEP(509, xr0, xr2, 1, 0, 1);
  STEP(510, xr1, xr0, 0, 0, 1);
  STEP(511, xr2, xr1, 1, 0, 0);

  // ---- MLP head: h_512 in sH[0] ----
  {
    int p = tid >> 4, q = tid & 15;
#pragma unroll
    for (int pass = 0; pass < 2; pass++) {
      int f = q + pass * 16;
      if (f < F_DIM) {
        float acc = fc1_b[e * F_DIM + f];
        const float* w1 = fc1_w + (size_t)e * (F_DIM * 128) + f * 128;
        for (int k = 0; k < 128; k++) {
          int off = (p * 256 + k * 2) ^ ((p & 7) << 4);
          float h = bf2f(*(const unsigned short*)(hb + off)) +
                    bf2f(*(const unsigned short*)(hb + 4096 + off));
          acc = fmaf(h, w1[k], acc);
        }
        sZ[p * F_DIM + f] = ftanh(acc);
      }
    }
  }
  __syncthreads();
  if (tid < BM) {
    float acc = fc2_b[e];
#pragma unroll
    for (int f = 0; f < F_DIM; f++)
      acc += sZ[tid * F_DIM + f] * fc2_w[e * F_DIM + f];
    if (tid < nr) outp[p0 + tid] = acc;
  }
#undef STEP
#undef HWRITE
#undef XPROJ
#undef LOADX
}

// ---------------- Kernel 4: weighted combine ----------------
__global__ void k_combine(const float* __restrict__ sel_g,
                          const int* __restrict__ pair_of,
                          const float* __restrict__ outp,
                          float* __restrict__ y) {
  int b = blockIdx.x * blockDim.x + threadIdx.x;
  if (b < B_SZ)
    y[b] = sel_g[2 * b] * outp[pair_of[2 * b]] +
           sel_g[2 * b + 1] * outp[pair_of[2 * b + 1]];
}

extern "C" void kernel_launch(void* const* d_in, const int* in_sizes, int n_in,
                              void* d_out, int out_size, void* d_ws,
                              size_t ws_size, hipStream_t stream) {
  (void)in_sizes; (void)n_in; (void)out_size; (void)ws_size;
  const float* x      = (const float*)d_in[0];
  const float* w_gate = (const float*)d_in[1];
  const float* W_ih   = (const float*)d_in[2];
  const float* W_hh   = (const float*)d_in[3];
  const float* b_ih   = (const float*)d_in[4];
  const float* b_hh   = (const float*)d_in[5];
  const float* fc1_w  = (const float*)d_in[6];
  const float* fc1_b  = (const float*)d_in[7];
  const float* fc2_w  = (const float*)d_in[8];
  const float* fc2_b  = (const float*)d_in[9];
  float* out = (float*)d_out;  // [0..511] = y, [512] = loss

  float* logits = (float*)d_ws;            // 4096 f32
  float* sel_g  = logits + 4096;           // 1024 f32
  int*   pair_b = (int*)(sel_g + 1024);    // 1024 i32
  int*   pair_of= pair_b + 1024;           // 1024 i32
  int*   blk_e  = pair_of + 1024;          // 128 i32
  int*   blk_p0 = blk_e + 128;             // 128 i32
  int*   blk_nr = blk_p0 + 128;            // 128 i32
  int*   nblk   = blk_nr + 128;            // 8 i32
  float* outp   = (float*)(nblk + 8);      // 1024 f32

  k_mean_logits<<<B_SZ, 512, 0, stream>>>(x, w_gate, logits);
  k_gate<<<1, 512, 0, stream>>>(logits, sel_g, pair_b, pair_of, blk_e, blk_p0,
                                blk_nr, nblk, out + 512);
  k_rnn<<<MAXBLK, 256, 0, stream>>>(x, W_ih, W_hh, b_ih, b_hh, fc1_w, fc1_b,
                                    fc2_w, fc2_b, pair_b, blk_e, blk_p0,
                                    blk_nr, nblk, outp);
  k_combine<<<2, 256, 0, stream>>>(sel_g, pair_of, outp, out);
}

// Round 5
// 578.131 us; speedup vs baseline: 1.7451x; 1.2244x over previous
//
#include <hip/hip_runtime.h>
#include <math.h>

#define B_SZ 512
#define S_SZ 512
#define E_NUM 8
#define F_DIM 20
#define BM 16          // pairs per RNN block (full MFMA N-tile)
#define MAXBLK 72      // >= sum_e ceil(cnt_e/16) <= 71

typedef __attribute__((ext_vector_type(8))) short bf16x8;
typedef __attribute__((ext_vector_type(4))) float f32x4;
typedef __attribute__((ext_vector_type(4))) unsigned int u32x4;
#define MFMA(a, b, c) __builtin_amdgcn_mfma_f32_16x16x32_bf16(a, b, c, 0, 0, 0)

__device__ __forceinline__ unsigned short f2bf(float f) {  // RNE
  unsigned u = __float_as_uint(f);
  u += 0x7FFFu + ((u >> 16) & 1u);
  return (unsigned short)(u >> 16);
}
__device__ __forceinline__ float bf2f(unsigned short h) {
  return __uint_as_float(((unsigned)h) << 16);
}
__device__ __forceinline__ unsigned pack2_hi(float a, float b) {  // trunc pair
  return (__float_as_uint(a) >> 16) | (__float_as_uint(b) & 0xFFFF0000u);
}
__device__ __forceinline__ float hi_f(float a) {
  return __uint_as_float(__float_as_uint(a) & 0xFFFF0000u);
}
// 8 floats -> hi/lo bf16x8 via truncation split
__device__ __forceinline__ void cvtX(const float4 a, const float4 b,
                                     bf16x8* hi, bf16x8* lo) {
  u32x4 h, l;
  h[0] = pack2_hi(a.x, a.y); h[1] = pack2_hi(a.z, a.w);
  h[2] = pack2_hi(b.x, b.y); h[3] = pack2_hi(b.z, b.w);
  l[0] = pack2_hi(a.x - hi_f(a.x), a.y - hi_f(a.y));
  l[1] = pack2_hi(a.z - hi_f(a.z), a.w - hi_f(a.w));
  l[2] = pack2_hi(b.x - hi_f(b.x), b.y - hi_f(b.y));
  l[3] = pack2_hi(b.z - hi_f(b.z), b.w - hi_f(b.w));
  *hi = *(bf16x8*)&h;
  *lo = *(bf16x8*)&l;
}
// 8 floats -> hi/lo bf16x8 via RNE split (one-time weight conversion)
__device__ __forceinline__ void cvt8r(float4 a, float4 b, bf16x8* hi, bf16x8* lo) {
  float v[8] = {a.x, a.y, a.z, a.w, b.x, b.y, b.z, b.w};
  bf16x8 h, l;
#pragma unroll
  for (int j = 0; j < 8; j++) {
    unsigned short hb = f2bf(v[j]);
    h[j] = (short)hb;
    l[j] = (short)f2bf(v[j] - bf2f(hb));
  }
  *hi = h; *lo = l;
}
__device__ __forceinline__ float ftanh(float x) {
  float e = __expf(x + x);  // x->+inf: e=inf -> rcp=0 -> 1; x->-inf: e=0 -> -1
  float r;
  asm("v_rcp_f32 %0, %1" : "=v"(r) : "v"(e + 1.0f));
  return fmaf(-2.0f, r, 1.0f);
}

// raw barrier: no compiler vmcnt(0) drain -> global prefetch stays in flight
#define BAR() do {                                        \
  asm volatile("s_waitcnt lgkmcnt(0)" ::: "memory");      \
  __builtin_amdgcn_s_barrier();                           \
  asm volatile("" ::: "memory");                          \
} while (0)

// ---------------- Kernel 1: x_mean + logits ----------------
__global__ __launch_bounds__(512) void k_mean_logits(
    const float* __restrict__ x, const float* __restrict__ w_gate,
    float* __restrict__ logits) {
  __shared__ float sm[512];
  __shared__ float xm[128];
  int b = blockIdx.x;
  int t = threadIdx.x;
  int i = t & 127, s0 = t >> 7;
  const float* xb = x + (size_t)b * (S_SZ * 128);
  float acc = 0.f;
  for (int s = s0; s < S_SZ; s += 4) acc += xb[s * 128 + i];
  sm[t] = acc;
  __syncthreads();
  if (t < 128)
    xm[t] = (sm[t] + sm[t + 128] + sm[t + 256] + sm[t + 384]) * (1.0f / 512.0f);
  __syncthreads();
  if (t < E_NUM) {
    float acc2 = 0.f;
    for (int ii = 0; ii < 128; ii++) acc2 += xm[ii] * w_gate[ii * E_NUM + t];
    logits[b * E_NUM + t] = acc2;
  }
}

// ------- Kernel 2: top-2 gates + CV^2 loss + expert compaction -------
__global__ __launch_bounds__(512) void k_gate(
    const float* __restrict__ logits, float* __restrict__ sel_g,
    int* __restrict__ pair_b, int* __restrict__ pair_of,
    int* __restrict__ blk_e, int* __restrict__ blk_p0,
    int* __restrict__ blk_nr, int* __restrict__ nblk,
    float* __restrict__ loss_out) {
  __shared__ float gmat[512][8];
  __shared__ int cnt[8], base[8], pos[8];
  __shared__ float imps[8];
  int t = threadIdx.x;
  if (t < 8) { cnt[t] = 0; pos[t] = 0; }
  float lv[8];
#pragma unroll
  for (int e = 0; e < 8; e++) {
    lv[e] = logits[t * 8 + e];
    gmat[t][e] = 0.f;
  }
  __syncthreads();
  float v0 = -INFINITY, v1 = -INFINITY;
  int i0 = 0, i1 = 0;
#pragma unroll
  for (int e = 0; e < 8; e++) {
    float v = lv[e];
    if (v > v0) { v1 = v0; i1 = i0; v0 = v; i0 = e; }
    else if (v > v1) { v1 = v; i1 = e; }
  }
  float ex = expf(v1 - v0);
  float inv = 1.0f / (1.0f + ex);
  float g0 = inv, g1 = ex * inv;
  gmat[t][i0] = g0;
  gmat[t][i1] = g1;
  atomicAdd(&cnt[i0], 1);
  atomicAdd(&cnt[i1], 1);
  sel_g[t * 2] = g0;
  sel_g[t * 2 + 1] = g1;
  __syncthreads();
  if (t == 0) {
    int o = 0;
    for (int e = 0; e < 8; e++) { base[e] = o; o += cnt[e]; }
    int nb = 0;
    for (int e = 0; e < 8; e++)
      for (int off = 0; off < cnt[e]; off += BM) {
        blk_e[nb] = e;
        blk_p0[nb] = base[e] + off;
        blk_nr[nb] = min(BM, cnt[e] - off);
        nb++;
      }
    *nblk = nb;
  }
  if (t < 8) {
    float s = 0.f;
    for (int bb = 0; bb < 512; bb++) s += gmat[bb][t];
    imps[t] = s;
  }
  __syncthreads();
  {
    int r = atomicAdd(&pos[i0], 1);
    int p = base[i0] + r;
    pair_b[p] = t;
    pair_of[t * 2] = p;
  }
  {
    int r = atomicAdd(&pos[i1], 1);
    int p = base[i1] + r;
    pair_b[p] = t;
    pair_of[t * 2 + 1] = p;
  }
  if (t == 0) {
    float mi = 0.f, ml = 0.f;
#pragma unroll
    for (int e = 0; e < 8; e++) { mi += imps[e]; ml += (float)cnt[e]; }
    mi *= 0.125f; ml *= 0.125f;
    float vi = 0.f, vl = 0.f;
#pragma unroll
    for (int e = 0; e < 8; e++) {
      float di = imps[e] - mi; vi += di * di;
      float dl = (float)cnt[e] - ml; vl += dl * dl;
    }
    vi *= (1.0f / 7.0f);
    vl *= (1.0f / 7.0f);
    loss_out[0] = 0.01f * (vi / (mi * mi + 1e-10f) + vl / (ml * ml + 1e-10f));
  }
}

// -------- Kernel 3a: x-projection GEMM -> P (fp32, workspace) --------
// P layout: [grp][s][hq(32)][pair(16)][4f32]; includes b_ih+b_hh.
// grid = MAXBLK x 8 step-groups; block = 256 thr; no LDS, no barriers.
__global__ __launch_bounds__(256, 1) void k_xproj(
    const float* __restrict__ x, const float* __restrict__ W_ih,
    const float* __restrict__ b_ih, const float* __restrict__ b_hh,
    const int* __restrict__ pair_b, const int* __restrict__ blk_e,
    const int* __restrict__ blk_p0, const int* __restrict__ blk_nr,
    const int* __restrict__ nblk, float* __restrict__ P) {
  int grp = blockIdx.x >> 3, sgrp = blockIdx.x & 7;
  if (grp >= *nblk) return;
  int e = blk_e[grp], p0 = blk_p0[grp], nr = blk_nr[grp];
  int tid = threadIdx.x;
  int lane = tid & 63, g = lane >> 4, ln = lane & 15;
  int MT0 = (tid >> 6) * 2;

  bf16x8 wih_h[2][4], wih_l[2][4];
#pragma unroll
  for (int mt = 0; mt < 2; mt++) {
    int row = (MT0 + mt) * 16 + ln;
    const float* bi = W_ih + (size_t)e * 16384 + row * 128;
#pragma unroll
    for (int ks = 0; ks < 4; ks++) {
      int k0 = ks * 32 + g * 8;
      cvt8r(*(const float4*)(bi + k0), *(const float4*)(bi + k0 + 4),
            &wih_h[mt][ks], &wih_l[mt][ks]);
    }
  }
  f32x4 biasv[2];
#pragma unroll
  for (int mt = 0; mt < 2; mt++)
#pragma unroll
    for (int r = 0; r < 4; r++) {
      int h = (MT0 + mt) * 16 + g * 4 + r;
      biasv[mt][r] = b_ih[e * 128 + h] + b_hh[e * 128 + h];
    }
  int bidx = pair_b[p0 + (ln < nr ? ln : 0)];
  const char* xlb = (const char*)x + (size_t)bidx * (S_SZ * 512) +
                    (size_t)sgrp * (64 * 512) + g * 32;
  float* Pb = P + ((size_t)grp * 512 + sgrp * 64) * 2048;
  int wo0 = ((MT0 + 0) * 4 + g) * 64 + ln * 4;
  int wo1 = ((MT0 + 1) * 4 + g) * 64 + ln * 4;
  const f32x4 Z4 = {0.f, 0.f, 0.f, 0.f};

#define XLOAD(XR, S0)                                                        \
  _Pragma("unroll") for (int j = 0; j < 8; j++)                              \
      XR[j] = *(const float4*)(xlb + (size_t)(S0) * 512 + (j >> 1) * 128 +   \
                               (j & 1) * 16);
#define XPROC(XR, S0)                                                        \
  do {                                                                       \
    bf16x8 Xh[4], Xl[4];                                                     \
    _Pragma("unroll") for (int ks = 0; ks < 4; ks++)                         \
        cvtX(XR[2 * ks], XR[2 * ks + 1], &Xh[ks], &Xl[ks]);                  \
    {                                                                        \
      f32x4 pA = biasv[0], pB = Z4, pC = Z4;                                 \
      _Pragma("unroll") for (int ks = 0; ks < 4; ks++)                       \
          pA = MFMA(wih_h[0][ks], Xh[ks], pA);                               \
      _Pragma("unroll") for (int ks = 0; ks < 4; ks++)                       \
          pB = MFMA(wih_l[0][ks], Xh[ks], pB);                               \
      _Pragma("unroll") for (int ks = 0; ks < 4; ks++)                       \
          pC = MFMA(wih_h[0][ks], Xl[ks], pC);                               \
      *(f32x4*)(Pb + (size_t)(S0) * 2048 + wo0) = pA + pB + pC;              \
    }                                                                        \
    {                                                                        \
      f32x4 pA = biasv[1], pB = Z4, pC = Z4;                                 \
      _Pragma("unroll") for (int ks = 0; ks < 4; ks++)                       \
          pA = MFMA(wih_h[1][ks], Xh[ks], pA);                               \
      _Pragma("unroll") for (int ks = 0; ks < 4; ks++)                       \
          pB = MFMA(wih_l[1][ks], Xh[ks], pB);                               \
      _Pragma("unroll") for (int ks = 0; ks < 4; ks++)                       \
          pC = MFMA(wih_h[1][ks], Xl[ks], pC);                               \
      *(f32x4*)(Pb + (size_t)(S0) * 2048 + wo1) = pA + pB + pC;              \
    }                                                                        \
  } while (0)

  float4 xrA[8], xrB[8];
  XLOAD(xrA, 0);
#pragma unroll 1
  for (int s = 0; s < 64; s += 2) {
    XLOAD(xrB, s + 1);
    XPROC(xrA, s);
    if (s + 2 < 64) { XLOAD(xrA, s + 2); }
    XPROC(xrB, s + 1);
  }
#undef XPROC
#undef XLOAD
}

// -------- Kernel 3b: recurrent MFMA RNN consuming precomputed P --------
__global__ __launch_bounds__(256, 1) void k_rnn_p(
    const float* __restrict__ P, const float* __restrict__ W_hh,
    const float* __restrict__ fc1_w, const float* __restrict__ fc1_b,
    const float* __restrict__ fc2_w, const float* __restrict__ fc2_b,
    const int* __restrict__ blk_e, const int* __restrict__ blk_p0,
    const int* __restrict__ blk_nr, const int* __restrict__ nblk,
    float* __restrict__ outp) {
  __shared__ unsigned short sH[2][2][BM * 128];  // [parity][hi/lo] 16 KB
  __shared__ float sZ[BM * F_DIM];

  int blk = blockIdx.x;
  if (blk >= *nblk) return;
  int e = blk_e[blk], p0 = blk_p0[blk], nr = blk_nr[blk];
  int tid = threadIdx.x;
  int lane = tid & 63, g = lane >> 4, ln = lane & 15;
  int MT0 = (tid >> 6) * 2;

  bf16x8 whh_h[2][4], whh_l[2][4];
#pragma unroll
  for (int mt = 0; mt < 2; mt++) {
    int row = (MT0 + mt) * 16 + ln;
    const float* bh = W_hh + (size_t)e * 16384 + row * 128;
#pragma unroll
    for (int ks = 0; ks < 4; ks++) {
      int k0 = ks * 32 + g * 8;
      cvt8r(*(const float4*)(bh + k0), *(const float4*)(bh + k0 + 4),
            &whh_h[mt][ks], &whh_l[mt][ks]);
    }
  }
  // zero parity-0 H (hi+lo = first 8 KB)
#pragma unroll
  for (int it = 0; it < 8; it++) ((unsigned int*)sH)[tid + it * 256] = 0;

  // per-lane P base (bytes); step stride 8192B
  const char* pb0 = (const char*)P +
      (((size_t)blk * 512) * 32 + ((size_t)(MT0 + 0) * 4 + g)) * 256 + ln * 16;
  const char* pb1 = (const char*)P +
      (((size_t)blk * 512) * 32 + ((size_t)(MT0 + 1) * 4 + g)) * 256 + ln * 16;

  // LDS byte offsets (XOR swizzle on bits 4-6; all offsets < 4096)
  int swz = (ln & 7) << 4;
  int rdoff[4], wroff[2][2];
#pragma unroll
  for (int ks = 0; ks < 4; ks++) rdoff[ks] = (ln * 256 + ks * 64 + g * 16) ^ swz;
#pragma unroll
  for (int mt = 0; mt < 2; mt++)
#pragma unroll
    for (int c = 0; c < 2; c++)
      wroff[mt][c] = (ln * 256 + (MT0 + mt) * 32 + g * 8 + c * 4) ^ swz;
  char* hb = (char*)&sH[0][0][0];

  const f32x4 Z4 = {0.f, 0.f, 0.f, 0.f};
  f32x4 P0[2], P1[2], P2[2];

#define PLOAD(PN, S)                                                         \
  do {                                                                       \
    PN[0] = *(const f32x4*)(pb0 + (size_t)(S)*8192);                         \
    PN[1] = *(const f32x4*)(pb1 + (size_t)(S)*8192);                         \
  } while (0)

#define HWRITE(PRE, MT, PAR)                                                 \
  do {                                                                       \
    float t0 = ftanh(PRE[0]), t1 = ftanh(PRE[1]);                            \
    float t2 = ftanh(PRE[2]), t3 = ftanh(PRE[3]);                            \
    unsigned hw0 = pack2_hi(t0, t1), hw1 = pack2_hi(t2, t3);                 \
    unsigned lw0 = pack2_hi(t0 - hi_f(t0), t1 - hi_f(t1));                   \
    unsigned lw1 = pack2_hi(t2 - hi_f(t2), t3 - hi_f(t3));                   \
    *(unsigned*)(hb + ((PAR) ^ 1) * 8192 + wroff[MT][0]) = hw0;              \
    *(unsigned*)(hb + ((PAR) ^ 1) * 8192 + wroff[MT][1]) = hw1;              \
    *(unsigned*)(hb + ((PAR) ^ 1) * 8192 + 4096 + wroff[MT][0]) = lw0;       \
    *(unsigned*)(hb + ((PAR) ^ 1) * 8192 + 4096 + wroff[MT][1]) = lw1;       \
  } while (0)

#define PSTEP(S, PU, PN, PAR, DOLOAD)                                        \
  do {                                                                       \
    bf16x8 Hh[4], Hl[4];                                                     \
    _Pragma("unroll") for (int ks = 0; ks < 4; ks++) {                       \
      Hh[ks] = *(const bf16x8*)(hb + (PAR)*8192 + rdoff[ks]);                \
      Hl[ks] = *(const bf16x8*)(hb + (PAR)*8192 + 4096 + rdoff[ks]);         \
    }                                                                        \
    if (DOLOAD) { PLOAD(PN, (S) + 2); }                                      \
    f32x4 pre0, pre1;                                                        \
    {                                                                        \
      f32x4 aA = PU[0], aB = Z4, aC = Z4;                                    \
      _Pragma("unroll") for (int ks = 0; ks < 4; ks++)                       \
          aA = MFMA(whh_h[0][ks], Hh[ks], aA);                               \
      _Pragma("unroll") for (int ks = 0; ks < 4; ks++)                       \
          aB = MFMA(whh_l[0][ks], Hh[ks], aB);                               \
      _Pragma("unroll") for (int ks = 0; ks < 4; ks++)                       \
          aC = MFMA(whh_h[0][ks], Hl[ks], aC);                               \
      pre0 = aA + aB + aC;                                                   \
    }                                                                        \
    {                                                                        \
      f32x4 aA = PU[1], aB = Z4, aC = Z4;                                    \
      _Pragma("unroll") for (int ks = 0; ks < 4; ks++)                       \
          aA = MFMA(whh_h[1][ks], Hh[ks], aA);                               \
      _Pragma("unroll") for (int ks = 0; ks < 4; ks++)                       \
          aB = MFMA(whh_l[1][ks], Hh[ks], aB);                               \
      _Pragma("unroll") for (int ks = 0; ks < 4; ks++)                       \
          aC = MFMA(whh_h[1][ks], Hl[ks], aC);                               \
      pre1 = aA + aB + aC;                                                   \
    }                                                                        \
    HWRITE(pre0, 0, PAR);                                                    \
    HWRITE(pre1, 1, PAR);                                                    \
    BAR();                                                                   \
  } while (0)

  PLOAD(P0, 0);
  PLOAD(P1, 1);
  BAR();  // H zeros visible

#pragma unroll 1
  for (int s6 = 0; s6 < 504; s6 += 6) {
    PSTEP(s6 + 0, P0, P2, 0, 1);
    PSTEP(s6 + 1, P1, P0, 1, 1);
    PSTEP(s6 + 2, P2, P1, 0, 1);
    PSTEP(s6 + 3, P0, P2, 1, 1);
    PSTEP(s6 + 4, P1, P0, 0, 1);
    PSTEP(s6 + 5, P2, P1, 1, 1);
  }
  PSTEP(504, P0, P2, 0, 1);
  PSTEP(505, P1, P0, 1, 1);
  PSTEP(506, P2, P1, 0, 1);
  PSTEP(507, P0, P2, 1, 1);
  PSTEP(508, P1, P0, 0, 1);
  PSTEP(509, P2, P1, 1, 1);
  PSTEP(510, P0, P2, 0, 0);
  PSTEP(511, P1, P0, 1, 0);

  // ---- MLP head: h_512 in sH[0] ----
  {
    int p = tid >> 4, q = tid & 15;
#pragma unroll
    for (int pass = 0; pass < 2; pass++) {
      int f = q + pass * 16;
      if (f < F_DIM) {
        float acc = fc1_b[e * F_DIM + f];
        const float* w1 = fc1_w + (size_t)e * (F_DIM * 128) + f * 128;
        for (int k = 0; k < 128; k++) {
          int off = (p * 256 + k * 2) ^ ((p & 7) << 4);
          float h = bf2f(*(const unsigned short*)(hb + off)) +
                    bf2f(*(const unsigned short*)(hb + 4096 + off));
          acc = fmaf(h, w1[k], acc);
        }
        sZ[p * F_DIM + f] = ftanh(acc);
      }
    }
  }
  __syncthreads();
  if (tid < BM) {
    float acc = fc2_b[e];
#pragma unroll
    for (int f = 0; f < F_DIM; f++)
      acc += sZ[tid * F_DIM + f] * fc2_w[e * F_DIM + f];
    if (tid < nr) outp[p0 + tid] = acc;
  }
#undef PSTEP
#undef HWRITE
#undef PLOAD
}

// -------- Kernel 3-fallback: round-4 fused RNN (used if ws too small) ----
__global__ __launch_bounds__(256, 1) void k_rnn_fused(
    const float* __restrict__ x, const float* __restrict__ W_ih,
    const float* __restrict__ W_hh, const float* __restrict__ b_ih,
    const float* __restrict__ b_hh, const float* __restrict__ fc1_w,
    const float* __restrict__ fc1_b, const float* __restrict__ fc2_w,
    const float* __restrict__ fc2_b, const int* __restrict__ pair_b,
    const int* __restrict__ blk_e, const int* __restrict__ blk_p0,
    const int* __restrict__ blk_nr, const int* __restrict__ nblk,
    float* __restrict__ outp) {
  __shared__ unsigned short sH[2][2][BM * 128];
  __shared__ float sZ[BM * F_DIM];

  int blk = blockIdx.x;
  if (blk >= *nblk) return;
  int e = blk_e[blk], p0 = blk_p0[blk], nr = blk_nr[blk];
  int tid = threadIdx.x;
  int lane = tid & 63, g = lane >> 4, ln = lane & 15;
  int MT0 = (tid >> 6) * 2;

  bf16x8 whh_h[2][4], whh_l[2][4], wih_h[2][4], wih_l[2][4];
#pragma unroll
  for (int mt = 0; mt < 2; mt++) {
    int row = (MT0 + mt) * 16 + ln;
    const float* bh = W_hh + (size_t)e * 16384 + row * 128;
    const float* bi = W_ih + (size_t)e * 16384 + row * 128;
#pragma unroll
    for (int ks = 0; ks < 4; ks++) {
      int k0 = ks * 32 + g * 8;
      cvt8r(*(const float4*)(bh + k0), *(const float4*)(bh + k0 + 4),
            &whh_h[mt][ks], &whh_l[mt][ks]);
      cvt8r(*(const float4*)(bi + k0), *(const float4*)(bi + k0 + 4),
            &wih_h[mt][ks], &wih_l[mt][ks]);
    }
  }
  f32x4 biasv[2];
#pragma unroll
  for (int mt = 0; mt < 2; mt++)
#pragma unroll
    for (int r = 0; r < 4; r++) {
      int h = (MT0 + mt) * 16 + g * 4 + r;
      biasv[mt][r] = b_ih[e * 128 + h] + b_hh[e * 128 + h];
    }
#pragma unroll
  for (int it = 0; it < 8; it++) ((unsigned int*)sH)[tid + it * 256] = 0;

  int bidx = pair_b[p0 + (ln < nr ? ln : 0)];
  const char* xlb = (const char*)x + (size_t)bidx * (S_SZ * 512) + g * 32;

  int swz = (ln & 7) << 4;
  int rdoff[4], wroff[2][2];
#pragma unroll
  for (int ks = 0; ks < 4; ks++) rdoff[ks] = (ln * 256 + ks * 64 + g * 16) ^ swz;
#pragma unroll
  for (int mt = 0; mt < 2; mt++)
#pragma unroll
    for (int c = 0; c < 2; c++)
      wroff[mt][c] = (ln * 256 + (MT0 + mt) * 32 + g * 8 + c * 4) ^ swz;
  char* hb = (char*)&sH[0][0][0];

  const f32x4 Z4 = {0.f, 0.f, 0.f, 0.f};
  f32x4 Pc0, Pc1;
  float4 xr0[8], xr1[8], xr2[8];

#define LOADX(XR, S0)                                                        \
  _Pragma("unroll") for (int j = 0; j < 8; j++)                              \
      XR[j] = *(const float4*)(xlb + (size_t)(S0) * 512 + (j >> 1) * 128 +   \
                               (j & 1) * 16);

#define XPROJ(XU)                                                            \
  do {                                                                       \
    bf16x8 Xh[4], Xl[4];                                                     \
    _Pragma("unroll") for (int ks = 0; ks < 4; ks++)                         \
        cvtX(XU[2 * ks], XU[2 * ks + 1], &Xh[ks], &Xl[ks]);                  \
    {                                                                        \
      f32x4 pA = biasv[0], pB = Z4, pC = Z4;                                 \
      _Pragma("unroll") for (int ks = 0; ks < 4; ks++)                       \
          pA = MFMA(wih_h[0][ks], Xh[ks], pA);                               \
      _Pragma("unroll") for (int ks = 0; ks < 4; ks++)                       \
          pB = MFMA(wih_l[0][ks], Xh[ks], pB);                               \
      _Pragma("unroll") for (int ks = 0; ks < 4; ks++)                       \
          pC = MFMA(wih_h[0][ks], Xl[ks], pC);                               \
      Pc0 = pA + pB + pC;                                                    \
    }                                                                        \
    {                                                                        \
      f32x4 pA = biasv[1], pB = Z4, pC = Z4;                                 \
      _Pragma("unroll") for (int ks = 0; ks < 4; ks++)                       \
          pA = MFMA(wih_h[1][ks], Xh[ks], pA);                               \
      _Pragma("unroll") for (int ks = 0; ks < 4; ks++)                       \
          pB = MFMA(wih_l[1][ks], Xh[ks], pB);                               \
      _Pragma("unroll") for (int ks = 0; ks < 4; ks++)                       \
          pC = MFMA(wih_h[1][ks], Xl[ks], pC);                               \
      Pc1 = pA + pB + pC;                                                    \
    }                                                                        \
  } while (0)

#define HWRITE(PRE, MT, PAR)                                                 \
  do {                                                                       \
    float t0 = ftanh(PRE[0]), t1 = ftanh(PRE[1]);                            \
    float t2 = ftanh(PRE[2]), t3 = ftanh(PRE[3]);                            \
    unsigned hw0 = pack2_hi(t0, t1), hw1 = pack2_hi(t2, t3);                 \
    unsigned lw0 = pack2_hi(t0 - hi_f(t0), t1 - hi_f(t1));                   \
    unsigned lw1 = pack2_hi(t2 - hi_f(t2), t3 - hi_f(t3));                   \
    *(unsigned*)(hb + ((PAR) ^ 1) * 8192 + wroff[MT][0]) = hw0;              \
    *(unsigned*)(hb + ((PAR) ^ 1) * 8192 + wroff[MT][1]) = hw1;              \
    *(unsigned*)(hb + ((PAR) ^ 1) * 8192 + 4096 + wroff[MT][0]) = lw0;       \
    *(unsigned*)(hb + ((PAR) ^ 1) * 8192 + 4096 + wroff[MT][1]) = lw1;       \
  } while (0)

#define STEP(S, XU, XN, PAR, DOLOAD, DOXP)                                   \
  do {                                                                       \
    bf16x8 Hh[4], Hl[4];                                                     \
    _Pragma("unroll") for (int ks = 0; ks < 4; ks++) {                       \
      Hh[ks] = *(const bf16x8*)(hb + (PAR)*8192 + rdoff[ks]);                \
      Hl[ks] = *(const bf16x8*)(hb + (PAR)*8192 + 4096 + rdoff[ks]);         \
    }                                                                        \
    if (DOLOAD) { LOADX(XN, (S) + 3); }                                      \
    f32x4 pre0, pre1;                                                        \
    {                                                                        \
      f32x4 aA = Pc0, aB = Z4, aC = Z4;                                      \
      _Pragma("unroll") for (int ks = 0; ks < 4; ks++)                       \
          aA = MFMA(whh_h[0][ks], Hh[ks], aA);                               \
      _Pragma("unroll") for (int ks = 0; ks < 4; ks++)                       \
          aB = MFMA(whh_l[0][ks], Hh[ks], aB);                               \
      _Pragma("unroll") for (int ks = 0; ks < 4; ks++)                       \
          aC = MFMA(whh_h[0][ks], Hl[ks], aC);                               \
      pre0 = aA + aB + aC;                                                   \
    }                                                                        \
    {                                                                        \
      f32x4 aA = Pc1, aB = Z4, aC = Z4;                                      \
      _Pragma("unroll") for (int ks = 0; ks < 4; ks++)                       \
          aA = MFMA(whh_h[1][ks], Hh[ks], aA);                               \
      _Pragma("unroll") for (int ks = 0; ks < 4; ks++)                       \
          aB = MFMA(whh_l[1][ks], Hh[ks], aB);                               \
      _Pragma("unroll") for (int ks = 0; ks < 4; ks++)                       \
          aC = MFMA(whh_h[1][ks], Hl[ks], aC);                               \
      pre1 = aA + aB + aC;                                                   \
    }                                                                        \
    if (DOXP) { XPROJ(XU); }                                                 \
    HWRITE(pre0, 0, PAR);                                                    \
    HWRITE(pre1, 1, PAR);                                                    \
    BAR();                                                                   \
  } while (0)

  LOADX(xr0, 0);
  LOADX(xr1, 1);
  LOADX(xr2, 2);
  XPROJ(xr0);
  BAR();

#pragma unroll 1
  for (int s6 = 0; s6 < 504; s6 += 6) {
    STEP(s6 + 0, xr1, xr0, 0, 1, 1);
    STEP(s6 + 1, xr2, xr1, 1, 1, 1);
    STEP(s6 + 2, xr0, xr2, 0, 1, 1);
    STEP(s6 + 3, xr1, xr0, 1, 1, 1);
    STEP(s6 + 4, xr2, xr1, 0, 1, 1);
    STEP(s6 + 5, xr0, xr2, 1, 1, 1);
  }
  STEP(504, xr1, xr0, 0, 1, 1);
  STEP(505, xr2, xr1, 1, 1, 1);
  STEP(506, xr0, xr2, 0, 1, 1);
  STEP(507, xr1, xr0, 1, 1, 1);
  STEP(508, xr2, xr1, 0, 1, 1);
  STEP(509, xr0, xr2, 1, 0, 1);
  STEP(510, xr1, xr0, 0, 0, 1);
  STEP(511, xr2, xr1, 1, 0, 0);

  {
    int p = tid >> 4, q = tid & 15;
#pragma unroll
    for (int pass = 0; pass < 2; pass++) {
      int f = q + pass * 16;
      if (f < F_DIM) {
        float acc = fc1_b[e * F_DIM + f];
        const float* w1 = fc1_w + (size_t)e * (F_DIM * 128) + f * 128;
        for (int k = 0; k < 128; k++) {
          int off = (p * 256 + k * 2) ^ ((p & 7) << 4);
          float h = bf2f(*(const unsigned short*)(hb + off)) +
                    bf2f(*(const unsigned short*)(hb + 4096 + off));
          acc = fmaf(h, w1[k], acc);
        }
        sZ[p * F_DIM + f] = ftanh(acc);
      }
    }
  }
  __syncthreads();
  if (tid < BM) {
    float acc = fc2_b[e];
#pragma unroll
    for (int f = 0; f < F_DIM; f++)
      acc += sZ[tid * F_DIM + f] * fc2_w[e * F_DIM + f];
    if (tid < nr) outp[p0 + tid] = acc;
  }
#undef STEP
#undef HWRITE
#undef XPROJ
#undef LOADX
}

// ---------------- Kernel 4: weighted combine ----------------
__global__ void k_combine(const float* __restrict__ sel_g,
                          const int* __restrict__ pair_of,
                          const float* __restrict__ outp,
                          float* __restrict__ y) {
  int b = blockIdx.x * blockDim.x + threadIdx.x;
  if (b < B_SZ)
    y[b] = sel_g[2 * b] * outp[pair_of[2 * b]] +
           sel_g[2 * b + 1] * outp[pair_of[2 * b + 1]];
}

extern "C" void kernel_launch(void* const* d_in, const int* in_sizes, int n_in,
                              void* d_out, int out_size, void* d_ws,
                              size_t ws_size, hipStream_t stream) {
  (void)in_sizes; (void)n_in; (void)out_size;
  const float* x      = (const float*)d_in[0];
  const float* w_gate = (const float*)d_in[1];
  const float* W_ih   = (const float*)d_in[2];
  const float* W_hh   = (const float*)d_in[3];
  const float* b_ih   = (const float*)d_in[4];
  const float* b_hh   = (const float*)d_in[5];
  const float* fc1_w  = (const float*)d_in[6];
  const float* fc1_b  = (const float*)d_in[7];
  const float* fc2_w  = (const float*)d_in[8];
  const float* fc2_b  = (const float*)d_in[9];
  float* out = (float*)d_out;  // [0..511] = y, [512] = loss

  float* logits = (float*)d_ws;            // 4096 f32
  float* sel_g  = logits + 4096;           // 1024 f32
  int*   pair_b = (int*)(sel_g + 1024);    // 1024 i32
  int*   pair_of= pair_b + 1024;           // 1024 i32
  int*   blk_e  = pair_of + 1024;          // 128 i32
  int*   blk_p0 = blk_e + 128;             // 128 i32
  int*   blk_nr = blk_p0 + 128;            // 128 i32
  int*   nblk   = blk_nr + 128;            // 8 i32
  float* outp   = (float*)(nblk + 8);      // 1024 f32
  float* P      = (float*)((char*)d_ws + 65536);
  size_t need = 65536 + (size_t)MAXBLK * 512 * 2048 * 4;  // 64KB + 288MiB

  k_mean_logits<<<B_SZ, 512, 0, stream>>>(x, w_gate, logits);
  k_gate<<<1, 512, 0, stream>>>(logits, sel_g, pair_b, pair_of, blk_e, blk_p0,
                                blk_nr, nblk, out + 512);
  if (ws_size >= need) {
    k_xproj<<<MAXBLK * 8, 256, 0, stream>>>(x, W_ih, b_ih, b_hh, pair_b,
                                            blk_e, blk_p0, blk_nr, nblk, P);
    k_rnn_p<<<MAXBLK, 256, 0, stream>>>(P, W_hh, fc1_w, fc1_b, fc2_w, fc2_b,
                                        blk_e, blk_p0, blk_nr, nblk, outp);
  } else {
    k_rnn_fused<<<MAXBLK, 256, 0, stream>>>(x, W_ih, W_hh, b_ih, b_hh, fc1_w,
                                            fc1_b, fc2_w, fc2_b, pair_b,
                                            blk_e, blk_p0, blk_nr, nblk, outp);
  }
  k_combine<<<2, 256, 0, stream>>>(sel_g, pair_of, outp, out);
}

// Round 6
// 518.234 us; speedup vs baseline: 1.9468x; 1.1156x over previous
//
#include <hip/hip_runtime.h>
#include <math.h>

#define B_SZ 512
#define S_SZ 512
#define E_NUM 8
#define F_DIM 20
#define BM 16          // pairs per RNN block (full MFMA N-tile)
#define MAXBLK 72      // >= sum_e ceil(cnt_e/16) <= 71
#define SGRP 16        // xproj step-groups per pair-group
#define SSTEPS (S_SZ / SGRP)

typedef __attribute__((ext_vector_type(8))) short bf16x8;
typedef __attribute__((ext_vector_type(4))) float f32x4;
typedef __attribute__((ext_vector_type(4))) unsigned int u32x4;
#define MFMA(a, b, c) __builtin_amdgcn_mfma_f32_16x16x32_bf16(a, b, c, 0, 0, 0)

__device__ __forceinline__ unsigned short f2bf(float f) {  // RNE
  unsigned u = __float_as_uint(f);
  u += 0x7FFFu + ((u >> 16) & 1u);
  return (unsigned short)(u >> 16);
}
__device__ __forceinline__ float bf2f(unsigned short h) {
  return __uint_as_float(((unsigned)h) << 16);
}
// {a.hi16, b.hi16} -> one dword via v_perm_b32
__device__ __forceinline__ unsigned pack2_hi(float a, float b) {
  return __builtin_amdgcn_perm(__float_as_uint(b), __float_as_uint(a),
                               0x07060302u);
}
__device__ __forceinline__ float hi_f(float a) {
  return __uint_as_float(__float_as_uint(a) & 0xFFFF0000u);
}
// 8 floats -> hi/lo bf16x8 via truncation split
__device__ __forceinline__ void cvtX(const float4 a, const float4 b,
                                     bf16x8* hi, bf16x8* lo) {
  u32x4 h, l;
  h[0] = pack2_hi(a.x, a.y); h[1] = pack2_hi(a.z, a.w);
  h[2] = pack2_hi(b.x, b.y); h[3] = pack2_hi(b.z, b.w);
  l[0] = pack2_hi(a.x - hi_f(a.x), a.y - hi_f(a.y));
  l[1] = pack2_hi(a.z - hi_f(a.z), a.w - hi_f(a.w));
  l[2] = pack2_hi(b.x - hi_f(b.x), b.y - hi_f(b.y));
  l[3] = pack2_hi(b.z - hi_f(b.z), b.w - hi_f(b.w));
  *hi = *(bf16x8*)&h;
  *lo = *(bf16x8*)&l;
}
// 8 floats -> hi/lo bf16x8 via RNE split (one-time weight conversion)
__device__ __forceinline__ void cvt8r(float4 a, float4 b, bf16x8* hi, bf16x8* lo) {
  float v[8] = {a.x, a.y, a.z, a.w, b.x, b.y, b.z, b.w};
  bf16x8 h, l;
#pragma unroll
  for (int j = 0; j < 8; j++) {
    unsigned short hb = f2bf(v[j]);
    h[j] = (short)hb;
    l[j] = (short)f2bf(v[j] - bf2f(hb));
  }
  *hi = h; *lo = l;
}
__device__ __forceinline__ float ftanh(float x) {
  float e = __expf(x + x);  // x->+inf: e=inf -> rcp=0 -> 1; x->-inf: e=0 -> -1
  float r;
  asm("v_rcp_f32 %0, %1" : "=v"(r) : "v"(e + 1.0f));
  return fmaf(-2.0f, r, 1.0f);  // rcp ~1ulp: tanh err ~2e-7 << split noise
}

// raw barrier: no compiler vmcnt(0) drain -> global prefetch stays in flight
#define BAR() do {                                        \
  asm volatile("s_waitcnt lgkmcnt(0)" ::: "memory");      \
  __builtin_amdgcn_s_barrier();                           \
  asm volatile("" ::: "memory");                          \
} while (0)

// ---------------- Kernel 1: x_mean + logits ----------------
__global__ __launch_bounds__(512) void k_mean_logits(
    const float* __restrict__ x, const float* __restrict__ w_gate,
    float* __restrict__ logits) {
  __shared__ float sm[512];
  __shared__ float xm[128];
  int b = blockIdx.x;
  int t = threadIdx.x;
  int i = t & 127, s0 = t >> 7;
  const float* xb = x + (size_t)b * (S_SZ * 128);
  float acc = 0.f;
  for (int s = s0; s < S_SZ; s += 4) acc += xb[s * 128 + i];
  sm[t] = acc;
  __syncthreads();
  if (t < 128)
    xm[t] = (sm[t] + sm[t + 128] + sm[t + 256] + sm[t + 384]) * (1.0f / 512.0f);
  __syncthreads();
  if (t < E_NUM) {
    float acc2 = 0.f;
    for (int ii = 0; ii < 128; ii++) acc2 += xm[ii] * w_gate[ii * E_NUM + t];
    logits[b * E_NUM + t] = acc2;
  }
}

// ------- Kernel 2: top-2 gates + CV^2 loss + expert compaction -------
__global__ __launch_bounds__(512) void k_gate(
    const float* __restrict__ logits, float* __restrict__ sel_g,
    int* __restrict__ pair_b, int* __restrict__ pair_of,
    int* __restrict__ blk_e, int* __restrict__ blk_p0,
    int* __restrict__ blk_nr, int* __restrict__ nblk,
    float* __restrict__ loss_out) {
  __shared__ float gmat[512][8];
  __shared__ int cnt[8], base[8], pos[8];
  __shared__ float imps[8];
  int t = threadIdx.x;
  if (t < 8) { cnt[t] = 0; pos[t] = 0; }
  float lv[8];
#pragma unroll
  for (int e = 0; e < 8; e++) {
    lv[e] = logits[t * 8 + e];
    gmat[t][e] = 0.f;
  }
  __syncthreads();
  float v0 = -INFINITY, v1 = -INFINITY;
  int i0 = 0, i1 = 0;
#pragma unroll
  for (int e = 0; e < 8; e++) {
    float v = lv[e];
    if (v > v0) { v1 = v0; i1 = i0; v0 = v; i0 = e; }
    else if (v > v1) { v1 = v; i1 = e; }
  }
  float ex = expf(v1 - v0);
  float inv = 1.0f / (1.0f + ex);
  float g0 = inv, g1 = ex * inv;
  gmat[t][i0] = g0;
  gmat[t][i1] = g1;
  atomicAdd(&cnt[i0], 1);
  atomicAdd(&cnt[i1], 1);
  sel_g[t * 2] = g0;
  sel_g[t * 2 + 1] = g1;
  __syncthreads();
  if (t == 0) {
    int o = 0;
    for (int e = 0; e < 8; e++) { base[e] = o; o += cnt[e]; }
    int nb = 0;
    for (int e = 0; e < 8; e++)
      for (int off = 0; off < cnt[e]; off += BM) {
        blk_e[nb] = e;
        blk_p0[nb] = base[e] + off;
        blk_nr[nb] = min(BM, cnt[e] - off);
        nb++;
      }
    *nblk = nb;
  }
  if (t < 8) {
    float s = 0.f;
    for (int bb = 0; bb < 512; bb++) s += gmat[bb][t];
    imps[t] = s;
  }
  __syncthreads();
  {
    int r = atomicAdd(&pos[i0], 1);
    int p = base[i0] + r;
    pair_b[p] = t;
    pair_of[t * 2] = p;
  }
  {
    int r = atomicAdd(&pos[i1], 1);
    int p = base[i1] + r;
    pair_b[p] = t;
    pair_of[t * 2 + 1] = p;
  }
  if (t == 0) {
    float mi = 0.f, ml = 0.f;
#pragma unroll
    for (int e = 0; e < 8; e++) { mi += imps[e]; ml += (float)cnt[e]; }
    mi *= 0.125f; ml *= 0.125f;
    float vi = 0.f, vl = 0.f;
#pragma unroll
    for (int e = 0; e < 8; e++) {
      float di = imps[e] - mi; vi += di * di;
      float dl = (float)cnt[e] - ml; vl += dl * dl;
    }
    vi *= (1.0f / 7.0f);
    vl *= (1.0f / 7.0f);
    loss_out[0] = 0.01f * (vi / (mi * mi + 1e-10f) + vl / (ml * ml + 1e-10f));
  }
}

// -------- Kernel 3a: x-projection GEMM -> P (fp32, workspace) --------
// P layout: [grp][s][hq(32)][pair(16)][4f32]; includes b_ih+b_hh.
// grid = MAXBLK x SGRP step-groups; 256 thr; VGPR<=128 for 4 waves/SIMD TLP.
__global__ __launch_bounds__(256, 2) void k_xproj(
    const float* __restrict__ x, const float* __restrict__ W_ih,
    const float* __restrict__ b_ih, const float* __restrict__ b_hh,
    const int* __restrict__ pair_b, const int* __restrict__ blk_e,
    const int* __restrict__ blk_p0, const int* __restrict__ blk_nr,
    const int* __restrict__ nblk, float* __restrict__ P) {
  int grp = blockIdx.x >> 4, sgrp = blockIdx.x & 15;
  if (grp >= *nblk) return;
  int e = blk_e[grp], p0 = blk_p0[grp], nr = blk_nr[grp];
  int tid = threadIdx.x;
  int lane = tid & 63, g = lane >> 4, ln = lane & 15;
  int MT0 = (tid >> 6) * 2;

  bf16x8 wih_h[2][4], wih_l[2][4];
#pragma unroll
  for (int mt = 0; mt < 2; mt++) {
    int row = (MT0 + mt) * 16 + ln;
    const float* bi = W_ih + (size_t)e * 16384 + row * 128;
#pragma unroll
    for (int ks = 0; ks < 4; ks++) {
      int k0 = ks * 32 + g * 8;
      cvt8r(*(const float4*)(bi + k0), *(const float4*)(bi + k0 + 4),
            &wih_h[mt][ks], &wih_l[mt][ks]);
    }
  }
  f32x4 biasv[2];
#pragma unroll
  for (int mt = 0; mt < 2; mt++)
#pragma unroll
    for (int r = 0; r < 4; r++) {
      int h = (MT0 + mt) * 16 + g * 4 + r;
      biasv[mt][r] = b_ih[e * 128 + h] + b_hh[e * 128 + h];
    }
  int bidx = pair_b[p0 + (ln < nr ? ln : 0)];
  const char* xlb = (const char*)x + (size_t)bidx * (S_SZ * 512) +
                    (size_t)sgrp * (SSTEPS * 512) + g * 32;
  float* Pb = P + ((size_t)grp * 512 + sgrp * SSTEPS) * 2048;
  int wo0 = ((MT0 + 0) * 4 + g) * 64 + ln * 4;
  int wo1 = ((MT0 + 1) * 4 + g) * 64 + ln * 4;

  float4 xr[8];
#pragma unroll 1
  for (int s = 0; s < SSTEPS; s++) {
#pragma unroll
    for (int j = 0; j < 8; j++)
      xr[j] = *(const float4*)(xlb + (size_t)s * 512 + (j >> 1) * 128 +
                               (j & 1) * 16);
    bf16x8 Xh[4], Xl[4];
#pragma unroll
    for (int ks = 0; ks < 4; ks++)
      cvtX(xr[2 * ks], xr[2 * ks + 1], &Xh[ks], &Xl[ks]);
    {
      f32x4 pA = biasv[0];
#pragma unroll
      for (int ks = 0; ks < 4; ks++) pA = MFMA(wih_h[0][ks], Xh[ks], pA);
#pragma unroll
      for (int ks = 0; ks < 4; ks++) pA = MFMA(wih_l[0][ks], Xh[ks], pA);
#pragma unroll
      for (int ks = 0; ks < 4; ks++) pA = MFMA(wih_h[0][ks], Xl[ks], pA);
      *(f32x4*)(Pb + (size_t)s * 2048 + wo0) = pA;
    }
    {
      f32x4 pA = biasv[1];
#pragma unroll
      for (int ks = 0; ks < 4; ks++) pA = MFMA(wih_h[1][ks], Xh[ks], pA);
#pragma unroll
      for (int ks = 0; ks < 4; ks++) pA = MFMA(wih_l[1][ks], Xh[ks], pA);
#pragma unroll
      for (int ks = 0; ks < 4; ks++) pA = MFMA(wih_h[1][ks], Xl[ks], pA);
      *(f32x4*)(Pb + (size_t)s * 2048 + wo1) = pA;
    }
  }
}

// -------- Kernel 3b: recurrent MFMA RNN consuming precomputed P --------
// Single-accumulator MFMA chains (C-forwarding at issue rate), perm packs,
// b64 H-writes, no-NR tanh. Only H (16KB) round-trips LDS.
__global__ __launch_bounds__(256, 1) void k_rnn_p(
    const float* __restrict__ P, const float* __restrict__ W_hh,
    const float* __restrict__ fc1_w, const float* __restrict__ fc1_b,
    const float* __restrict__ fc2_w, const float* __restrict__ fc2_b,
    const int* __restrict__ blk_e, const int* __restrict__ blk_p0,
    const int* __restrict__ blk_nr, const int* __restrict__ nblk,
    float* __restrict__ outp) {
  __shared__ unsigned short sH[2][2][BM * 128];  // [parity][hi/lo] 16 KB
  __shared__ float sZ[BM * F_DIM];

  int blk = blockIdx.x;
  if (blk >= *nblk) return;
  int e = blk_e[blk], p0 = blk_p0[blk], nr = blk_nr[blk];
  int tid = threadIdx.x;
  int lane = tid & 63, g = lane >> 4, ln = lane & 15;
  int MT0 = (tid >> 6) * 2;

  bf16x8 whh_h[2][4], whh_l[2][4];
#pragma unroll
  for (int mt = 0; mt < 2; mt++) {
    int row = (MT0 + mt) * 16 + ln;
    const float* bh = W_hh + (size_t)e * 16384 + row * 128;
#pragma unroll
    for (int ks = 0; ks < 4; ks++) {
      int k0 = ks * 32 + g * 8;
      cvt8r(*(const float4*)(bh + k0), *(const float4*)(bh + k0 + 4),
            &whh_h[mt][ks], &whh_l[mt][ks]);
    }
  }
  // zero parity-0 H (hi+lo = first 8 KB)
#pragma unroll
  for (int it = 0; it < 8; it++) ((unsigned int*)sH)[tid + it * 256] = 0;

  // per-lane P base (bytes); step stride 8192B
  const char* pb0 = (const char*)P +
      (((size_t)blk * 512) * 32 + ((size_t)(MT0 + 0) * 4 + g)) * 256 + ln * 16;
  const char* pb1 = (const char*)P +
      (((size_t)blk * 512) * 32 + ((size_t)(MT0 + 1) * 4 + g)) * 256 + ln * 16;

  // LDS byte offsets (XOR swizzle on bits 4-6; all offsets < 4096)
  int swz = (ln & 7) << 4;
  int rdoff[4], wroff[2];
#pragma unroll
  for (int ks = 0; ks < 4; ks++) rdoff[ks] = (ln * 256 + ks * 64 + g * 16) ^ swz;
#pragma unroll
  for (int mt = 0; mt < 2; mt++)
    wroff[mt] = (ln * 256 + (MT0 + mt) * 32 + g * 8) ^ swz;
  char* hb = (char*)&sH[0][0][0];

  f32x4 P0[2], P1[2], P2[2];

#define PLOAD(PN, S)                                                         \
  do {                                                                       \
    PN[0] = *(const f32x4*)(pb0 + (size_t)(S)*8192);                         \
    PN[1] = *(const f32x4*)(pb1 + (size_t)(S)*8192);                         \
  } while (0)

#define HWRITE(PRE, MT, PAR)                                                 \
  do {                                                                       \
    float t0 = ftanh(PRE[0]), t1 = ftanh(PRE[1]);                            \
    float t2 = ftanh(PRE[2]), t3 = ftanh(PRE[3]);                            \
    uint2 hv = {pack2_hi(t0, t1), pack2_hi(t2, t3)};                         \
    uint2 lv = {pack2_hi(t0 - hi_f(t0), t1 - hi_f(t1)),                      \
                pack2_hi(t2 - hi_f(t2), t3 - hi_f(t3))};                     \
    *(uint2*)(hb + ((PAR) ^ 1) * 8192 + wroff[MT]) = hv;                     \
    *(uint2*)(hb + ((PAR) ^ 1) * 8192 + 4096 + wroff[MT]) = lv;              \
  } while (0)

#define PSTEP(S, PU, PN, PAR, DOLOAD)                                        \
  do {                                                                       \
    bf16x8 Hh[4], Hl[4];                                                     \
    _Pragma("unroll") for (int ks = 0; ks < 4; ks++) {                       \
      Hh[ks] = *(const bf16x8*)(hb + (PAR)*8192 + rdoff[ks]);                \
      Hl[ks] = *(const bf16x8*)(hb + (PAR)*8192 + 4096 + rdoff[ks]);         \
    }                                                                        \
    if (DOLOAD) { PLOAD(PN, (S) + 2); }                                      \
    f32x4 pre0 = PU[0];                                                      \
    _Pragma("unroll") for (int ks = 0; ks < 4; ks++)                         \
        pre0 = MFMA(whh_h[0][ks], Hh[ks], pre0);                             \
    _Pragma("unroll") for (int ks = 0; ks < 4; ks++)                         \
        pre0 = MFMA(whh_l[0][ks], Hh[ks], pre0);                             \
    _Pragma("unroll") for (int ks = 0; ks < 4; ks++)                         \
        pre0 = MFMA(whh_h[0][ks], Hl[ks], pre0);                             \
    f32x4 pre1 = PU[1];                                                      \
    _Pragma("unroll") for (int ks = 0; ks < 4; ks++)                         \
        pre1 = MFMA(whh_h[1][ks], Hh[ks], pre1);                             \
    _Pragma("unroll") for (int ks = 0; ks < 4; ks++)                         \
        pre1 = MFMA(whh_l[1][ks], Hh[ks], pre1);                             \
    _Pragma("unroll") for (int ks = 0; ks < 4; ks++)                         \
        pre1 = MFMA(whh_h[1][ks], Hl[ks], pre1);                             \
    HWRITE(pre0, 0, PAR);                                                    \
    HWRITE(pre1, 1, PAR);                                                    \
    BAR();                                                                   \
  } while (0)

  PLOAD(P0, 0);
  PLOAD(P1, 1);
  BAR();  // H zeros visible

#pragma unroll 1
  for (int s6 = 0; s6 < 504; s6 += 6) {
    PSTEP(s6 + 0, P0, P2, 0, 1);
    PSTEP(s6 + 1, P1, P0, 1, 1);
    PSTEP(s6 + 2, P2, P1, 0, 1);
    PSTEP(s6 + 3, P0, P2, 1, 1);
    PSTEP(s6 + 4, P1, P0, 0, 1);
    PSTEP(s6 + 5, P2, P1, 1, 1);
  }
  PSTEP(504, P0, P2, 0, 1);
  PSTEP(505, P1, P0, 1, 1);
  PSTEP(506, P2, P1, 0, 1);
  PSTEP(507, P0, P2, 1, 1);
  PSTEP(508, P1, P0, 0, 1);
  PSTEP(509, P2, P1, 1, 1);
  PSTEP(510, P0, P2, 0, 0);
  PSTEP(511, P1, P0, 1, 0);

  // ---- MLP head: h_512 in sH[0] ----
  {
    int p = tid >> 4, q = tid & 15;
#pragma unroll
    for (int pass = 0; pass < 2; pass++) {
      int f = q + pass * 16;
      if (f < F_DIM) {
        float acc = fc1_b[e * F_DIM + f];
        const float* w1 = fc1_w + (size_t)e * (F_DIM * 128) + f * 128;
        for (int k = 0; k < 128; k++) {
          int off = (p * 256 + k * 2) ^ ((p & 7) << 4);
          float h = bf2f(*(const unsigned short*)(hb + off)) +
                    bf2f(*(const unsigned short*)(hb + 4096 + off));
          acc = fmaf(h, w1[k], acc);
        }
        sZ[p * F_DIM + f] = ftanh(acc);
      }
    }
  }
  __syncthreads();
  if (tid < BM) {
    float acc = fc2_b[e];
#pragma unroll
    for (int f = 0; f < F_DIM; f++)
      acc += sZ[tid * F_DIM + f] * fc2_w[e * F_DIM + f];
    if (tid < nr) outp[p0 + tid] = acc;
  }
#undef PSTEP
#undef HWRITE
#undef PLOAD
}

// ---------------- Kernel 4: weighted combine ----------------
__global__ void k_combine(const float* __restrict__ sel_g,
                          const int* __restrict__ pair_of,
                          const float* __restrict__ outp,
                          float* __restrict__ y) {
  int b = blockIdx.x * blockDim.x + threadIdx.x;
  if (b < B_SZ)
    y[b] = sel_g[2 * b] * outp[pair_of[2 * b]] +
           sel_g[2 * b + 1] * outp[pair_of[2 * b + 1]];
}

extern "C" void kernel_launch(void* const* d_in, const int* in_sizes, int n_in,
                              void* d_out, int out_size, void* d_ws,
                              size_t ws_size, hipStream_t stream) {
  (void)in_sizes; (void)n_in; (void)out_size; (void)ws_size;
  const float* x      = (const float*)d_in[0];
  const float* w_gate = (const float*)d_in[1];
  const float* W_ih   = (const float*)d_in[2];
  const float* W_hh   = (const float*)d_in[3];
  const float* b_ih   = (const float*)d_in[4];
  const float* b_hh   = (const float*)d_in[5];
  const float* fc1_w  = (const float*)d_in[6];
  const float* fc1_b  = (const float*)d_in[7];
  const float* fc2_w  = (const float*)d_in[8];
  const float* fc2_b  = (const float*)d_in[9];
  float* out = (float*)d_out;  // [0..511] = y, [512] = loss

  float* logits = (float*)d_ws;            // 4096 f32
  float* sel_g  = logits + 4096;           // 1024 f32
  int*   pair_b = (int*)(sel_g + 1024);    // 1024 i32
  int*   pair_of= pair_b + 1024;           // 1024 i32
  int*   blk_e  = pair_of + 1024;          // 128 i32
  int*   blk_p0 = blk_e + 128;             // 128 i32
  int*   blk_nr = blk_p0 + 128;            // 128 i32
  int*   nblk   = blk_nr + 128;            // 8 i32
  float* outp   = (float*)(nblk + 8);      // 1024 f32
  float* P      = (float*)((char*)d_ws + 65536);  // 288 MiB (fits: round 5 ran)

  k_mean_logits<<<B_SZ, 512, 0, stream>>>(x, w_gate, logits);
  k_gate<<<1, 512, 0, stream>>>(logits, sel_g, pair_b, pair_of, blk_e, blk_p0,
                                blk_nr, nblk, out + 512);
  k_xproj<<<MAXBLK * SGRP, 256, 0, stream>>>(x, W_ih, b_ih, b_hh, pair_b,
                                             blk_e, blk_p0, blk_nr, nblk, P);
  k_rnn_p<<<MAXBLK, 256, 0, stream>>>(P, W_hh, fc1_w, fc1_b, fc2_w, fc2_b,
                                      blk_e, blk_p0, blk_nr, nblk, outp);
  k_combine<<<2, 256, 0, stream>>>(sel_g, pair_of, outp, out);
}